// Round 3
// baseline (35.780 us; speedup 1.0000x reference)
//
#include <hip/hip_runtime.h>
#include <math.h>

#define DT 0.2f
#define LEN_HIST 16
#define MAX_PRED 32

// ws float layout:
//   [0 .. 119]                K[t][4][2] for t = 1..15  (t-1 major, i*2+j)
//   [128 .. 128+3*len_pred)   (sx, sy, rho) per prediction step l

__global__ void kalman_setup_kernel(
    const float* __restrict__ vsx_p, const float* __restrict__ vsy_p,
    const float* __restrict__ asx_p, const float* __restrict__ asy_p,
    const float* __restrict__ GR_p,  const float* __restrict__ coefG_p,
    float* __restrict__ ws, int len_pred)
{
    if (threadIdx.x != 0 || blockIdx.x != 0) return;

    const float Gv0 = DT * DT * 0.5f, Gv1 = DT, Gv2 = DT * DT * 0.5f, Gv3 = DT;
    float ax2 = asx_p[0] * asx_p[0];
    float ay2 = asy_p[0] * asy_p[0];
    float g[4];
    g[0] = Gv0 * tanhf(coefG_p[0]);
    g[1] = Gv1 * tanhf(coefG_p[1]);
    g[2] = Gv2 * tanhf(coefG_p[2]);
    g[3] = Gv3 * tanhf(coefG_p[3]);
    float Q[4][4];
    #pragma unroll
    for (int i = 0; i < 4; ++i) {
        #pragma unroll
        for (int j = 0; j < 4; ++j) {
            float s = (i < 2) ? ((j < 2) ? ax2 : 1.0f)
                              : ((j < 2) ? 1.0f : ay2);
            Q[i][j] = g[i] * g[j] * s;
        }
    }
    float GR0 = GR_p[0], GR1 = GR_p[1];
    float R00 = GR0 * GR0, R01 = GR0 * GR1, R10 = GR1 * GR0, R11 = GR1 * GR1;
    float vsx2 = vsx_p[0] * vsx_p[0];
    float vsy2 = vsy_p[0] * vsy_p[0];

    float P[4][4] = {};
    P[0][0] = R00; P[1][1] = vsx2; P[2][2] = R11; P[3][3] = vsy2;

    // ---- filter covariance recursion: emit K_t ----
    #pragma unroll
    for (int t = 1; t < LEN_HIST; ++t) {
        float T[4][4];
        #pragma unroll
        for (int j = 0; j < 4; ++j) {
            T[0][j] = P[0][j] + DT * P[1][j];
            T[1][j] = P[1][j];
            T[2][j] = P[2][j] + DT * P[3][j];
            T[3][j] = P[3][j];
        }
        #pragma unroll
        for (int i = 0; i < 4; ++i) {
            P[i][0] = T[i][0] + DT * T[i][1] + Q[i][0];
            P[i][1] = T[i][1]               + Q[i][1];
            P[i][2] = T[i][2] + DT * T[i][3] + Q[i][2];
            P[i][3] = T[i][3]               + Q[i][3];
        }

        float S00 = P[0][0] + R00, S01 = P[0][2] + R01;
        float S10 = P[2][0] + R10, S11 = P[2][2] + R11;
        float inv = 1.0f / (S00 * S11 - S01 * S10);
        float Si00 =  S11 * inv, Si01 = -S01 * inv;
        float Si10 = -S10 * inv, Si11 =  S00 * inv;

        float K[4][2];
        #pragma unroll
        for (int i = 0; i < 4; ++i) {
            K[i][0] = P[i][0] * Si00 + P[i][2] * Si10;
            K[i][1] = P[i][0] * Si01 + P[i][2] * Si11;
        }
        #pragma unroll
        for (int i = 0; i < 4; ++i) {
            ws[(t - 1) * 8 + i * 2 + 0] = K[i][0];
            ws[(t - 1) * 8 + i * 2 + 1] = K[i][1];
        }

        // Joseph form update (matches reference numerics)
        float U[4][4];
        #pragma unroll
        for (int i = 0; i < 4; ++i) {
            #pragma unroll
            for (int j = 0; j < 4; ++j)
                U[i][j] = P[i][j] - K[i][0] * P[0][j] - K[i][1] * P[2][j];
        }
        float w[4];
        #pragma unroll
        for (int i = 0; i < 4; ++i)
            w[i] = K[i][0] * GR0 + K[i][1] * GR1;
        #pragma unroll
        for (int i = 0; i < 4; ++i) {
            #pragma unroll
            for (int j = 0; j < 4; ++j)
                P[i][j] = U[i][j] - U[i][0] * K[j][0] - U[i][2] * K[j][1] + w[i] * w[j];
        }
    }

    // ---- prediction covariance: emit (sx, sy, rho) per step ----
    for (int l = 0; l < len_pred; ++l) {
        float T[4][4];
        #pragma unroll
        for (int j = 0; j < 4; ++j) {
            T[0][j] = P[0][j] + DT * P[1][j];
            T[1][j] = P[1][j];
            T[2][j] = P[2][j] + DT * P[3][j];
            T[3][j] = P[3][j];
        }
        #pragma unroll
        for (int i = 0; i < 4; ++i) {
            P[i][0] = T[i][0] + DT * T[i][1] + Q[i][0];
            P[i][1] = T[i][1]               + Q[i][1];
            P[i][2] = T[i][2] + DT * T[i][3] + Q[i][2];
            P[i][3] = T[i][3]               + Q[i][3];
        }
        float sx = sqrtf(P[0][0]);
        float sy = sqrtf(P[2][2]);
        float rho = (P[0][2] + P[2][0]) / (2.0f * sx * sy);
        ws[128 + l * 3 + 0] = sx;
        ws[128 + l * 3 + 1] = sy;
        ws[128 + l * 3 + 2] = rho;
    }
}

__global__ __launch_bounds__(256) void kalman_track_kernel(
    const float* __restrict__ hist, const float* __restrict__ ws,
    float* __restrict__ out, int B, int len_pred)
{
    __shared__ float sK[15 * 8];
    __shared__ float sC[3 * MAX_PRED];

    int tid = threadIdx.x;
    // cooperative broadcast-table load (strided over the FULL table this time)
    for (int i = tid; i < 120; i += 256) sK[i] = ws[i];
    for (int i = tid; i < 3 * len_pred; i += 256) sC[i] = ws[128 + i];
    __syncthreads();

    int b = blockIdx.x * 256 + tid;
    if (b >= B) return;

    float2 z[LEN_HIST];
    #pragma unroll
    for (int t = 0; t < LEN_HIST; ++t)
        z[t] = *reinterpret_cast<const float2*>(hist + ((size_t)t * B + b) * 2);

    float X0 = z[0].x;
    float X1 = (z[1].x - z[0].x) / DT;
    float X2 = z[0].y;
    float X3 = (z[1].y - z[0].y) / DT;

    #pragma unroll
    for (int t = 1; t < LEN_HIST; ++t) {
        X0 += DT * X1;
        X2 += DT * X3;
        float y0 = z[t].x - X0;
        float y1 = z[t].y - X2;
        const float* K = &sK[(t - 1) * 8];
        X0 += K[0] * y0 + K[1] * y1;
        X1 += K[2] * y0 + K[3] * y1;
        X2 += K[4] * y0 + K[5] * y1;
        X3 += K[6] * y0 + K[7] * y1;
    }

    for (int l = 0; l < len_pred; ++l) {
        X0 += DT * X1;
        X2 += DT * X3;
        float* o = out + ((size_t)l * B + b) * 5;
        o[0] = X0;
        o[1] = X2;
        o[2] = sC[l * 3 + 0];
        o[3] = sC[l * 3 + 1];
        o[4] = sC[l * 3 + 2];
    }
}

extern "C" void kernel_launch(void* const* d_in, const int* in_sizes, int n_in,
                              void* d_out, int out_size, void* d_ws, size_t ws_size,
                              hipStream_t stream) {
    const float* hist  = (const float*)d_in[0];
    const float* vsx   = (const float*)d_in[1];
    const float* vsy   = (const float*)d_in[2];
    const float* asx   = (const float*)d_in[3];
    const float* asy   = (const float*)d_in[4];
    const float* GR    = (const float*)d_in[5];
    const float* coefG = (const float*)d_in[6];
    float* out = (float*)d_out;
    float* ws  = (float*)d_ws;

    int B = in_sizes[0] / (LEN_HIST * 2);
    int len_pred = out_size / (B * 5);
    if (len_pred > MAX_PRED) len_pred = MAX_PRED;

    kalman_setup_kernel<<<1, 64, 0, stream>>>(vsx, vsy, asx, asy, GR, coefG, ws, len_pred);

    int block = 256;
    int grid = (B + block - 1) / block;
    kalman_track_kernel<<<grid, block, 0, stream>>>(hist, ws, out, B, len_pred);
}

// Round 4
// 30.886 us; speedup vs baseline: 1.1585x; 1.1585x over previous
//
#include <hip/hip_runtime.h>
#include <math.h>

#define DT 0.2f
#define LEN_HIST 16
#define MAX_PRED 32
#define TPB 256            // threads per block
#define TRKPB (2 * TPB)    // tracks per block (2 tracks per thread)

__global__ __launch_bounds__(TPB) void kalman_fused(
    const float* __restrict__ hist,
    const float* __restrict__ vsx_p, const float* __restrict__ vsy_p,
    const float* __restrict__ asx_p, const float* __restrict__ asy_p,
    const float* __restrict__ GR_p,  const float* __restrict__ coefG_p,
    float* __restrict__ out, int B, int len_pred)
{
    __shared__ float sK[15 * 8];        // Kalman gains, t = 1..15
    __shared__ float sC[3 * MAX_PRED];  // (sx, sy, rho) per prediction step
    __shared__ float sT[4][2][320];     // per-wave store-transpose buffers

    const int tid  = threadIdx.x;
    const int base = blockIdx.x * TRKPB;
    const int bA   = base + tid;
    const int bB   = base + TPB + tid;
    const bool vA  = bA < B, vB = bB < B;
    const int iA   = vA ? bA : (B - 1);
    const int iB   = vB ? bB : (B - 1);

    // ---- issue all measurement loads first (latency hides under setup) ----
    float2 zA[LEN_HIST], zB[LEN_HIST];
    #pragma unroll
    for (int t = 0; t < LEN_HIST; ++t) {
        zA[t] = *reinterpret_cast<const float2*>(hist + ((size_t)t * B + iA) * 2);
        zB[t] = *reinterpret_cast<const float2*>(hist + ((size_t)t * B + iB) * 2);
    }

    // ---- shared covariance recursion (data-independent): once per block ----
    if (tid == 0) {
        const float Gv0 = DT * DT * 0.5f, Gv1 = DT, Gv2 = DT * DT * 0.5f, Gv3 = DT;
        float ax2 = asx_p[0] * asx_p[0];
        float ay2 = asy_p[0] * asy_p[0];
        float g[4];
        g[0] = Gv0 * tanhf(coefG_p[0]);
        g[1] = Gv1 * tanhf(coefG_p[1]);
        g[2] = Gv2 * tanhf(coefG_p[2]);
        g[3] = Gv3 * tanhf(coefG_p[3]);
        float Q[4][4];
        #pragma unroll
        for (int i = 0; i < 4; ++i)
            #pragma unroll
            for (int j = 0; j < 4; ++j) {
                float s = (i < 2) ? ((j < 2) ? ax2 : 1.0f)
                                  : ((j < 2) ? 1.0f : ay2);
                Q[i][j] = g[i] * g[j] * s;
            }
        float GR0 = GR_p[0], GR1 = GR_p[1];
        float R00 = GR0 * GR0, R01 = GR0 * GR1, R10 = GR1 * GR0, R11 = GR1 * GR1;
        float P[4][4] = {};
        P[0][0] = R00; P[1][1] = vsx_p[0] * vsx_p[0];
        P[2][2] = R11; P[3][3] = vsy_p[0] * vsy_p[0];

        #pragma unroll
        for (int t = 1; t < LEN_HIST; ++t) {
            float T[4][4];
            #pragma unroll
            for (int j = 0; j < 4; ++j) {
                T[0][j] = P[0][j] + DT * P[1][j];
                T[1][j] = P[1][j];
                T[2][j] = P[2][j] + DT * P[3][j];
                T[3][j] = P[3][j];
            }
            #pragma unroll
            for (int i = 0; i < 4; ++i) {
                P[i][0] = T[i][0] + DT * T[i][1] + Q[i][0];
                P[i][1] = T[i][1]                + Q[i][1];
                P[i][2] = T[i][2] + DT * T[i][3] + Q[i][2];
                P[i][3] = T[i][3]                + Q[i][3];
            }
            float S00 = P[0][0] + R00, S01 = P[0][2] + R01;
            float S10 = P[2][0] + R10, S11 = P[2][2] + R11;
            float inv = 1.0f / (S00 * S11 - S01 * S10);
            float Si00 =  S11 * inv, Si01 = -S01 * inv;
            float Si10 = -S10 * inv, Si11 =  S00 * inv;
            float K[4][2];
            #pragma unroll
            for (int i = 0; i < 4; ++i) {
                K[i][0] = P[i][0] * Si00 + P[i][2] * Si10;
                K[i][1] = P[i][0] * Si01 + P[i][2] * Si11;
                sK[(t - 1) * 8 + i * 2 + 0] = K[i][0];
                sK[(t - 1) * 8 + i * 2 + 1] = K[i][1];
            }
            float U[4][4];
            #pragma unroll
            for (int i = 0; i < 4; ++i)
                #pragma unroll
                for (int j = 0; j < 4; ++j)
                    U[i][j] = P[i][j] - K[i][0] * P[0][j] - K[i][1] * P[2][j];
            float w_[4];
            #pragma unroll
            for (int i = 0; i < 4; ++i)
                w_[i] = K[i][0] * GR0 + K[i][1] * GR1;
            #pragma unroll
            for (int i = 0; i < 4; ++i)
                #pragma unroll
                for (int j = 0; j < 4; ++j)
                    P[i][j] = U[i][j] - U[i][0] * K[j][0] - U[i][2] * K[j][1] + w_[i] * w_[j];
        }
        for (int l = 0; l < len_pred; ++l) {
            float T[4][4];
            #pragma unroll
            for (int j = 0; j < 4; ++j) {
                T[0][j] = P[0][j] + DT * P[1][j];
                T[1][j] = P[1][j];
                T[2][j] = P[2][j] + DT * P[3][j];
                T[3][j] = P[3][j];
            }
            #pragma unroll
            for (int i = 0; i < 4; ++i) {
                P[i][0] = T[i][0] + DT * T[i][1] + Q[i][0];
                P[i][1] = T[i][1]                + Q[i][1];
                P[i][2] = T[i][2] + DT * T[i][3] + Q[i][2];
                P[i][3] = T[i][3]                + Q[i][3];
            }
            float sx = sqrtf(P[0][0]);
            float sy = sqrtf(P[2][2]);
            sC[l * 3 + 0] = sx;
            sC[l * 3 + 1] = sy;
            sC[l * 3 + 2] = (P[0][2] + P[2][0]) / (2.0f * sx * sy);
        }
    }
    __syncthreads();

    // ---- per-track state filter (data-dependent part only) ----
    float A0 = zA[0].x, A1 = (zA[1].x - zA[0].x) / DT;
    float A2 = zA[0].y, A3 = (zA[1].y - zA[0].y) / DT;
    float B0 = zB[0].x, B1 = (zB[1].x - zB[0].x) / DT;
    float B2 = zB[0].y, B3 = (zB[1].y - zB[0].y) / DT;

    #pragma unroll
    for (int t = 1; t < LEN_HIST; ++t) {
        const float4 kx = *reinterpret_cast<const float4*>(&sK[(t - 1) * 8]);     // K00 K01 K10 K11
        const float4 ky = *reinterpret_cast<const float4*>(&sK[(t - 1) * 8 + 4]); // K20 K21 K30 K31
        A0 += DT * A1; A2 += DT * A3;
        float y0 = zA[t].x - A0, y1 = zA[t].y - A2;
        A0 += kx.x * y0 + kx.y * y1;
        A1 += kx.z * y0 + kx.w * y1;
        A2 += ky.x * y0 + ky.y * y1;
        A3 += ky.z * y0 + ky.w * y1;
        B0 += DT * B1; B2 += DT * B3;
        y0 = zB[t].x - B0; y1 = zB[t].y - B2;
        B0 += kx.x * y0 + kx.y * y1;
        B1 += kx.z * y0 + kx.w * y1;
        B2 += ky.x * y0 + ky.y * y1;
        B3 += ky.z * y0 + ky.w * y1;
    }

    // ---- prediction + coalesced store via per-wave LDS transpose ----
    const int lane = tid & 63, w = tid >> 6;
    float* bufA = &sT[w][0][0];
    float* bufB = &sT[w][1][0];
    const int gA = base + w * 64;        // first track of this wave's group A
    const int gB = base + TPB + w * 64;  // first track of group B
    const bool fullA = (gA + 63) < B;
    const bool fullB = (gB + 63) < B;
    const bool alignOK = (((size_t)B * 5) & 3) == 0;

    for (int l = 0; l < len_pred; ++l) {
        A0 += DT * A1; A2 += DT * A3;
        B0 += DT * B1; B2 += DT * B3;
        const float cx = sC[3 * l], cy = sC[3 * l + 1], cr = sC[3 * l + 2];

        if (fullA && alignOK) {
            __builtin_amdgcn_wave_barrier();
            bufA[lane * 5 + 0] = A0;
            bufA[lane * 5 + 1] = A2;
            bufA[lane * 5 + 2] = cx;
            bufA[lane * 5 + 3] = cy;
            bufA[lane * 5 + 4] = cr;
            __builtin_amdgcn_wave_barrier();
            float* oA = out + ((size_t)l * B + gA) * 5;
            *reinterpret_cast<float4*>(oA + lane * 4) =
                *reinterpret_cast<const float4*>(&bufA[lane * 4]);
            oA[256 + lane] = bufA[256 + lane];
        } else if (vA) {
            float* o = out + ((size_t)l * B + bA) * 5;
            o[0] = A0; o[1] = A2; o[2] = cx; o[3] = cy; o[4] = cr;
        }

        if (fullB && alignOK) {
            __builtin_amdgcn_wave_barrier();
            bufB[lane * 5 + 0] = B0;
            bufB[lane * 5 + 1] = B2;
            bufB[lane * 5 + 2] = cx;
            bufB[lane * 5 + 3] = cy;
            bufB[lane * 5 + 4] = cr;
            __builtin_amdgcn_wave_barrier();
            float* oB = out + ((size_t)l * B + gB) * 5;
            *reinterpret_cast<float4*>(oB + lane * 4) =
                *reinterpret_cast<const float4*>(&bufB[lane * 4]);
            oB[256 + lane] = bufB[256 + lane];
        } else if (vB) {
            float* o = out + ((size_t)l * B + bB) * 5;
            o[0] = B0; o[1] = B2; o[2] = cx; o[3] = cy; o[4] = cr;
        }
    }
}

extern "C" void kernel_launch(void* const* d_in, const int* in_sizes, int n_in,
                              void* d_out, int out_size, void* d_ws, size_t ws_size,
                              hipStream_t stream) {
    const float* hist  = (const float*)d_in[0];
    const float* vsx   = (const float*)d_in[1];
    const float* vsy   = (const float*)d_in[2];
    const float* asx   = (const float*)d_in[3];
    const float* asy   = (const float*)d_in[4];
    const float* GR    = (const float*)d_in[5];
    const float* coefG = (const float*)d_in[6];
    float* out = (float*)d_out;

    int B = in_sizes[0] / (LEN_HIST * 2);
    int len_pred = out_size / (B * 5);
    if (len_pred > MAX_PRED) len_pred = MAX_PRED;

    int grid = (B + TRKPB - 1) / TRKPB;
    kalman_fused<<<grid, TPB, 0, stream>>>(hist, vsx, vsy, asx, asy, GR, coefG,
                                           out, B, len_pred);
}